// Round 21
// baseline (240.809 us; speedup 1.0000x reference)
//
#include <hip/hip_runtime.h>
#include <hip/hip_cooperative_groups.h>
#include <hip/hip_bf16.h>
#include <math.h>

namespace cg = cooperative_groups;

#define BN_SCALE_F 0.99999500003749969f

typedef short short8v __attribute__((ext_vector_type(8)));
typedef float float4v __attribute__((ext_vector_type(4)));

// Single cooperative kernel, 512 blocks x 320 threads (2 blocks/CU co-resident).
// Phase 1: pool (+w1b/lw1r prep) grid-strided; grid.sync();
// Phase 2: gl (G-MFMA blocks 0..255, L blocks 256..511); grid.sync();
// Phase 3: final depthwise conv, one (n,tch) per block, two cv4 passes.

union MonoSmem {
  float poolbuf[6400];  // 25.6 KB
  struct {
    __hip_bfloat16 abuf[16][328];
    __hip_bfloat16 hbuf[16][612];
    float logits[48];
  } g;  // ~30.3 KB
  struct {
    float p[64][81];
    float z[75][20];
  } l;  // ~26.7 KB
};

__global__ __launch_bounds__(320) void mono_kernel(const float* __restrict__ x,
                                                   const float* __restrict__ g_w1,
                                                   const float* __restrict__ l_w1,
                                                   const float* __restrict__ g_w2,
                                                   const float* __restrict__ l_w2,
                                                   float* __restrict__ pooledT,
                                                   __hip_bfloat16* __restrict__ w1b,
                                                   float* __restrict__ lw1r,
                                                   float* __restrict__ kern,
                                                   float* __restrict__ la,
                                                   float* __restrict__ out) {
  cg::grid_group grid = cg::this_grid();
  __shared__ MonoSmem sm;
  int bid = blockIdx.x;
  int tid = threadIdx.x;
  int wave = tid >> 6, lane = tid & 63;

  // ---------------- Phase 1: pool + prep ----------------
  for (int u = bid; u < 4817; u += 512) {
    if (u < 4800) {
      const float4* src = (const float4*)(x + (size_t)u * 6400);
      float4* b4 = (float4*)sm.poolbuf;
#pragma unroll
      for (int it = 0; it < 5; ++it) {
        int i = tid + it * 320;
        b4[i] = src[i];
      }
      __syncthreads();
      if (wave < 4) {
        const float* p = sm.poolbuf + wave * 1600 + lane * 25;
        float s = 0.f;
#pragma unroll
        for (int v = 0; v < 25; ++v) s += p[v];
        pooledT[(size_t)(u * 4 + wave) * 64 + lane] = s * 0.04f;
      }
    } else if (u < 4816) {
      int b = u - 4800;
      for (int i = b * 256 + tid; i < 608 * 320; i += 16 * 256) {
        int j = i / 320, k = i - j * 320;
        float v = (j < 600 && k < 300) ? g_w1[(size_t)j * 300 + k] : 0.f;
        w1b[i] = __float2bfloat16(v);
      }
    } else {
      for (int i = tid; i < 3072; i += 320) {
        int o = i / 192;
        int rem = i - o * 192;
        int c = rem / 3;
        int k = rem - c * 3;
        lw1r[c * 48 + o * 3 + k] = l_w1[i];
      }
    }
    __syncthreads();
  }

  grid.sync();

  // ---------------- Phase 2: G (MFMA) + L ----------------
  if (bid < 256) {
    int r0 = bid * 16;
    int n = bid >> 2;
    int c0 = (bid & 3) * 16;
    for (int i = tid; i < 5120; i += 320) {
      int tt = i >> 4;
      int cc = i & 15;
      float v = (tt < 300) ? pooledT[((size_t)n * 300 + tt) * 64 + c0 + cc] : 0.f;
      sm.g.abuf[cc][tt] = __float2bfloat16(v);
    }
    __syncthreads();

    int row16 = lane & 15;
    int k8 = (lane >> 4) * 8;

    float4v acc[8];
#pragma unroll
    for (int q = 0; q < 8; ++q) acc[q] = (float4v){0.f, 0.f, 0.f, 0.f};

    const short* pb = (const short*)w1b + k8;
    const short* pa = (const short*)&sm.g.abuf[row16][k8];

    for (int kt = 0; kt < 10; ++kt) {
      short8v av = *(const short8v*)(pa + kt * 32);
#pragma unroll
      for (int q = 0; q < 8; ++q) {
        int jt = wave + 5 * q;
        if (jt < 38) {
          short8v bv = *(const short8v*)(pb + (size_t)(jt * 16 + row16) * 320 + kt * 32);
          acc[q] = __builtin_amdgcn_mfma_f32_16x16x32_bf16(av, bv, acc[q], 0, 0, 0);
        }
      }
    }

#pragma unroll
    for (int q = 0; q < 8; ++q) {
      int jt = wave + 5 * q;
      if (jt < 38) {
        int col = jt * 16 + row16;
#pragma unroll
        for (int reg = 0; reg < 4; ++reg) {
          int i = (lane >> 4) * 4 + reg;
          sm.g.hbuf[i][col] = __float2bfloat16(fmaxf(acc[q][reg] * BN_SCALE_F, 0.f));
        }
      }
    }
    __syncthreads();

    for (int o = wave; o < 48; o += 5) {
      int r = o / 3, k = o - r * 3;
      float s = 0.f;
#pragma unroll
      for (int q = 0; q < 10; ++q) {
        int jj = lane + q * 64;
        if (jj < 600) s = fmaf(__bfloat162float(sm.g.hbuf[r][jj]), g_w2[k * 600 + jj], s);
      }
#pragma unroll
      for (int off = 1; off < 64; off <<= 1) s += __shfl_xor(s, off, 64);
      if (lane == 0) sm.g.logits[o] = s;
    }
    __syncthreads();
    if (tid < 16) {
      float a = sm.g.logits[tid * 3 + 0];
      float b = sm.g.logits[tid * 3 + 1];
      float c = sm.g.logits[tid * 3 + 2];
      float m = fmaxf(a, fmaxf(b, c));
      float ea = expf(a - m), eb = expf(b - m), ec = expf(c - m);
      float inv = 1.f / (ea + eb + ec);
      size_t o = (size_t)(r0 + tid) * 3;
      kern[o] = ea * inv;
      kern[o + 1] = eb * inv;
      kern[o + 2] = ec * inv;
    }
  } else {
    int bid2 = bid - 256;
    int n = bid2 >> 2;
    int tc = bid2 & 3;
    int t0 = tc * 75;
    for (int i = tid; i < 77 * 64; i += 320) {
      int tt = i >> 6, c = i & 63;
      int gt = t0 - 1 + tt;
      sm.l.p[c][tt] = (gt >= 0 && gt < 300) ? pooledT[((size_t)n * 300 + gt) * 64 + c] : 0.f;
    }
    __syncthreads();
    if (tid < 256) {
      int og = __builtin_amdgcn_readfirstlane(tid >> 6);
      int tl = tid & 63;
      float acc[4] = {0.f, 0.f, 0.f, 0.f};
      const float* wb = lw1r + og * 12;
      for (int c = 0; c < 64; ++c) {
        const float* wr = wb + c * 48;  // uniform -> s_load_dwordx4
        float pk0 = sm.l.p[c][tl];
        float pk1 = sm.l.p[c][tl + 1];
        float pk2 = sm.l.p[c][tl + 2];
#pragma unroll
        for (int oi = 0; oi < 4; ++oi) {
          acc[oi] = fmaf(wr[oi * 3 + 0], pk0, acc[oi]);
          acc[oi] = fmaf(wr[oi * 3 + 1], pk1, acc[oi]);
          acc[oi] = fmaf(wr[oi * 3 + 2], pk2, acc[oi]);
        }
      }
      float4 zv;
      zv.x = fmaxf(acc[0] * BN_SCALE_F, 0.f);
      zv.y = fmaxf(acc[1] * BN_SCALE_F, 0.f);
      zv.z = fmaxf(acc[2] * BN_SCALE_F, 0.f);
      zv.w = fmaxf(acc[3] * BN_SCALE_F, 0.f);
      *(float4*)(&sm.l.z[tl][og * 4]) = zv;
    } else {
      int lane5 = tid - 256;
      int og = lane5 >> 4;
      int tlo = lane5 & 15;
      if (tlo < 11) {
        int tl = 64 + tlo;
        float acc[4] = {0.f, 0.f, 0.f, 0.f};
        for (int c = 0; c < 64; ++c) {
          const float* wr = lw1r + c * 48 + og * 12;
          float pk0 = sm.l.p[c][tl];
          float pk1 = sm.l.p[c][tl + 1];
          float pk2 = sm.l.p[c][tl + 2];
#pragma unroll
          for (int oi = 0; oi < 4; ++oi) {
            acc[oi] = fmaf(wr[oi * 3 + 0], pk0, acc[oi]);
            acc[oi] = fmaf(wr[oi * 3 + 1], pk1, acc[oi]);
            acc[oi] = fmaf(wr[oi * 3 + 2], pk2, acc[oi]);
          }
        }
        float4 zv;
        zv.x = fmaxf(acc[0] * BN_SCALE_F, 0.f);
        zv.y = fmaxf(acc[1] * BN_SCALE_F, 0.f);
        zv.z = fmaxf(acc[2] * BN_SCALE_F, 0.f);
        zv.w = fmaxf(acc[3] * BN_SCALE_F, 0.f);
        *(float4*)(&sm.l.z[tl][og * 4]) = zv;
      }
    }
    __syncthreads();
    {
      int c = tid / 5;
      int ts = tid - c * 5;
      const float4* w2v = (const float4*)(l_w2 + c * 16);
      float4 wA = w2v[0], wB = w2v[1], wC = w2v[2], wD = w2v[3];
      float* outp = la + (size_t)(n * 64 + c) * 300 + t0;
      for (int it = 0; it < 15; ++it) {
        int tl = ts + it * 5;
        const float4* zv = (const float4*)(&sm.l.z[tl][0]);
        float4 zA = zv[0], zB = zv[1], zC = zv[2], zD = zv[3];
        float s = zA.x * wA.x + zA.y * wA.y + zA.z * wA.z + zA.w * wA.w;
        s += zB.x * wB.x + zB.y * wB.y + zB.z * wB.z + zB.w * wB.w;
        s += zC.x * wC.x + zC.y * wC.y + zC.z * wC.z + zC.w * wC.w;
        s += zD.x * wD.x + zD.y * wD.y + zD.z * wD.z + zD.w * wD.w;
        outp[tl] = 1.f / (1.f + expf(-s));
      }
    }
  }

  grid.sync();

  // ---------------- Phase 3: final depthwise conv ----------------
  {
    int n = bid >> 3;
    int tch = bid & 7;
    int t0 = tch * 38;
    int tend = t0 + 38;
    if (tend > 300) tend = 300;

#pragma unroll 1
    for (int pass = 0; pass < 2; ++pass) {
      int cv4 = tid + pass * 320;
      if (cv4 >= 400) break;
      int e0 = cv4 * 4;
      int c0 = e0 / 25;
      int c3 = (e0 + 3) / 25;
      bool s1 = ((e0 + 1) / 25) != c0;
      bool s2 = ((e0 + 2) / 25) != c0;
      bool s3 = (c3 != c0);
      const float* lap0 = la + (size_t)(n * 64 + c0) * 300;
      const float* lap1 = la + (size_t)(n * 64 + c3) * 300;
      const float* kp0 = kern + (size_t)(n * 64 + c0) * 3;
      const float* kp1 = kern + (size_t)(n * 64 + c3) * 3;
      float k00 = kp0[0], k01 = kp0[1], k02 = kp0[2];
      float k10 = kp1[0], k11 = kp1[1], k12 = kp1[2];
      float4 K0 = {k00, s1 ? k10 : k00, s2 ? k10 : k00, s3 ? k10 : k00};
      float4 K1 = {k01, s1 ? k11 : k01, s2 ? k11 : k01, s3 ? k11 : k01};
      float4 K2 = {k02, s1 ? k12 : k02, s2 ? k12 : k02, s3 ? k12 : k02};

      const float4* xp = (const float4*)(x + (size_t)n * 480000) + cv4;
      float4* op = (float4*)(out + (size_t)n * 480000) + cv4;

#define LAMUL(dst, t)                                        \
      {                                                      \
        float l0 = lap0[(t)];                                \
        float l1 = lap1[(t)];                                \
        float4 xv = xp[(size_t)(t) * 400];                   \
        dst.x = xv.x * l0;                                   \
        dst.y = xv.y * (s1 ? l1 : l0);                       \
        dst.z = xv.z * (s2 ? l1 : l0);                       \
        dst.w = xv.w * (s3 ? l1 : l0);                       \
      }

      float4 am, ac, an;
      if (t0 > 0) {
        LAMUL(am, t0 - 1);
      } else {
        am = {0.f, 0.f, 0.f, 0.f};
      }
      LAMUL(ac, t0);
      for (int t = t0; t < tend; ++t) {
        if (t + 1 < 300) {
          LAMUL(an, t + 1);
        } else {
          an = {0.f, 0.f, 0.f, 0.f};
        }
        float4 o;
        o.x = fmaf(am.x, K0.x, fmaf(ac.x, K1.x, an.x * K2.x));
        o.y = fmaf(am.y, K0.y, fmaf(ac.y, K1.y, an.y * K2.y));
        o.z = fmaf(am.z, K0.z, fmaf(ac.z, K1.z, an.z * K2.z));
        o.w = fmaf(am.w, K0.w, fmaf(ac.w, K1.w, an.w * K2.w));
        op[(size_t)t * 400] = o;
        am = ac;
        ac = an;
      }
#undef LAMUL
    }
  }
}

extern "C" void kernel_launch(void* const* d_in, const int* in_sizes, int n_in,
                              void* d_out, int out_size, void* d_ws, size_t ws_size,
                              hipStream_t stream) {
  const float* x = (const float*)d_in[0];
  const float* g_w1 = (const float*)d_in[1];
  const float* g_w2 = (const float*)d_in[2];
  const float* l_w1 = (const float*)d_in[3];
  const float* l_w2 = (const float*)d_in[4];
  float* out = (float*)d_out;
  float* ws = (float*)d_ws;
  float* pooledT = ws;                                 // 1,228,800 floats
  float* kern = ws + 1228800;                          // 12,288
  float* lact = ws + 1228800 + 12288;                  // 1,228,800
  __hip_bfloat16* w1b = (__hip_bfloat16*)(ws + 2469888);  // 608*320 bf16
  float* lw1r = ws + 2469888 + 97280;                  // 3,072 floats

  void* args[] = {(void*)&x, (void*)&g_w1, (void*)&l_w1, (void*)&g_w2, (void*)&l_w2,
                  (void*)&pooledT, (void*)&w1b, (void*)&lw1r, (void*)&kern,
                  (void*)&lact, (void*)&out};
  hipLaunchCooperativeKernel((const void*)mono_kernel, dim3(512), dim3(320), args, 0,
                             stream);
}

// Round 22
// 111.462 us; speedup vs baseline: 2.1605x; 2.1605x over previous
//
#include <hip/hip_runtime.h>
#include <hip/hip_bf16.h>
#include <math.h>

#define BN_SCALE_F 0.99999500003749969f

typedef short short8v __attribute__((ext_vector_type(8)));
typedef float float4v __attribute__((ext_vector_type(4)));

// x: [N=64][T=300][C=64][V=25] fp32
// pooledT: [19200][64] f32   (nt-major; coalesced)
// laT:     [19200][64] f32   (nt-major local activation; coalesced consumer reads)
// w1b:     [608][320]  bf16  (G MFMA B)
// kern: [4096][3]   lw1r: [64][48]

// ---------------- Kernel 1: pool (0..4799) + w1b (4800..4815) + lw1r (4816) ----------------
__global__ __launch_bounds__(320) void pool_kernel(const float* __restrict__ x,
                                                   const float* __restrict__ g_w1,
                                                   const float* __restrict__ l_w1,
                                                   float* __restrict__ pooledT,
                                                   __hip_bfloat16* __restrict__ w1b,
                                                   float* __restrict__ lw1r) {
  __shared__ float buf[6400];
  int bid = blockIdx.x;
  int tid = threadIdx.x;
  if (bid < 4800) {
    const float4* src = (const float4*)(x + (size_t)bid * 6400);
    float4* b4 = (float4*)buf;
#pragma unroll
    for (int it = 0; it < 5; ++it) {
      int i = tid + it * 320;
      b4[i] = src[i];
    }
    __syncthreads();
    int wave = tid >> 6;
    int c = tid & 63;
    if (wave < 4) {
      const float* p = buf + wave * 1600 + c * 25;
      float s = 0.f;
#pragma unroll
      for (int v = 0; v < 25; ++v) s += p[v];
      pooledT[(size_t)(bid * 4 + wave) * 64 + c] = s * 0.04f;
    }
  } else if (bid < 4816) {
    int b = bid - 4800;
    for (int i = b * 256 + tid; i < 608 * 320; i += 16 * 256) {
      int j = i / 320, k = i - j * 320;
      float v = (j < 600 && k < 300) ? g_w1[(size_t)j * 300 + k] : 0.f;
      w1b[i] = __float2bfloat16(v);
    }
  } else {
    for (int i = tid; i < 3072; i += 320) {
      int o = i / 192;
      int rem = i - o * 192;
      int c = rem / 3;
      int k = rem - c * 3;
      lw1r[c * 48 + o * 3 + k] = l_w1[i];
    }
  }
}

// ---------------- Kernel 2: merged G (MFMA, LDS-staged A) + L branch ----------------
union GLSmem {
  struct {
    __hip_bfloat16 abuf[16][328];
    __hip_bfloat16 hbuf[16][612];
    float logits[48];
  } g;
  struct {
    float p[64][81];
    float z[75][20];
  } l;
};

__global__ __launch_bounds__(320) void gl_kernel(const float* __restrict__ pooledT,
                                                 const __hip_bfloat16* __restrict__ w1b,
                                                 const float* __restrict__ g_w2,  // [3][600]
                                                 const float* __restrict__ lw1r,  // [64][48]
                                                 const float* __restrict__ l_w2,  // [64][16]
                                                 float* __restrict__ kern,        // [4096][3]
                                                 float* __restrict__ laT) {       // [19200][64]
  __shared__ GLSmem sm;
  int bid = blockIdx.x;
  int tid = threadIdx.x;
  int wave = tid >> 6, lane = tid & 63;
  if (bid < 256) {
    // ---- G branch ----
    int r0 = bid * 16;
    int n = bid >> 2;
    int c0 = (bid & 3) * 16;
    for (int i = tid; i < 5120; i += 320) {
      int tt = i >> 4;
      int cc = i & 15;
      float v = (tt < 300) ? pooledT[((size_t)n * 300 + tt) * 64 + c0 + cc] : 0.f;
      sm.g.abuf[cc][tt] = __float2bfloat16(v);
    }
    __syncthreads();

    int row16 = lane & 15;
    int k8 = (lane >> 4) * 8;

    float4v acc[8];
#pragma unroll
    for (int q = 0; q < 8; ++q) acc[q] = (float4v){0.f, 0.f, 0.f, 0.f};

    const short* pb = (const short*)w1b + k8;
    const short* pa = (const short*)&sm.g.abuf[row16][k8];

    for (int kt = 0; kt < 10; ++kt) {
      short8v av = *(const short8v*)(pa + kt * 32);
#pragma unroll
      for (int q = 0; q < 8; ++q) {
        int jt = wave + 5 * q;
        if (jt < 38) {
          short8v bv = *(const short8v*)(pb + (size_t)(jt * 16 + row16) * 320 + kt * 32);
          acc[q] = __builtin_amdgcn_mfma_f32_16x16x32_bf16(av, bv, acc[q], 0, 0, 0);
        }
      }
    }

#pragma unroll
    for (int q = 0; q < 8; ++q) {
      int jt = wave + 5 * q;
      if (jt < 38) {
        int col = jt * 16 + row16;
#pragma unroll
        for (int reg = 0; reg < 4; ++reg) {
          int i = (lane >> 4) * 4 + reg;
          sm.g.hbuf[i][col] = __float2bfloat16(fmaxf(acc[q][reg] * BN_SCALE_F, 0.f));
        }
      }
    }
    __syncthreads();

    for (int o = wave; o < 48; o += 5) {
      int r = o / 3, k = o - r * 3;
      float s = 0.f;
#pragma unroll
      for (int q = 0; q < 10; ++q) {
        int jj = lane + q * 64;
        if (jj < 600) s = fmaf(__bfloat162float(sm.g.hbuf[r][jj]), g_w2[k * 600 + jj], s);
      }
#pragma unroll
      for (int off = 1; off < 64; off <<= 1) s += __shfl_xor(s, off, 64);
      if (lane == 0) sm.g.logits[o] = s;
    }
    __syncthreads();
    if (tid < 16) {
      float a = sm.g.logits[tid * 3 + 0];
      float b = sm.g.logits[tid * 3 + 1];
      float c = sm.g.logits[tid * 3 + 2];
      float m = fmaxf(a, fmaxf(b, c));
      float ea = expf(a - m), eb = expf(b - m), ec = expf(c - m);
      float inv = 1.f / (ea + eb + ec);
      size_t o = (size_t)(r0 + tid) * 3;
      kern[o] = ea * inv;
      kern[o + 1] = eb * inv;
      kern[o + 2] = ec * inv;
    }
  } else {
    // ---- L branch ----
    int bid2 = bid - 256;
    int n = bid2 >> 2;
    int tc = bid2 & 3;
    int t0 = tc * 75;
    for (int i = tid; i < 77 * 64; i += 320) {
      int tt = i >> 6, c = i & 63;
      int gt = t0 - 1 + tt;
      sm.l.p[c][tt] = (gt >= 0 && gt < 300) ? pooledT[((size_t)n * 300 + gt) * 64 + c] : 0.f;
    }
    __syncthreads();
    if (tid < 256) {
      int og = __builtin_amdgcn_readfirstlane(tid >> 6);
      int tl = tid & 63;
      float acc[4] = {0.f, 0.f, 0.f, 0.f};
      const float* wb = lw1r + og * 12;
      for (int c = 0; c < 64; ++c) {
        const float* wr = wb + c * 48;  // uniform -> s_load_dwordx4
        float pk0 = sm.l.p[c][tl];
        float pk1 = sm.l.p[c][tl + 1];
        float pk2 = sm.l.p[c][tl + 2];
#pragma unroll
        for (int oi = 0; oi < 4; ++oi) {
          acc[oi] = fmaf(wr[oi * 3 + 0], pk0, acc[oi]);
          acc[oi] = fmaf(wr[oi * 3 + 1], pk1, acc[oi]);
          acc[oi] = fmaf(wr[oi * 3 + 2], pk2, acc[oi]);
        }
      }
      float4 zv;
      zv.x = fmaxf(acc[0] * BN_SCALE_F, 0.f);
      zv.y = fmaxf(acc[1] * BN_SCALE_F, 0.f);
      zv.z = fmaxf(acc[2] * BN_SCALE_F, 0.f);
      zv.w = fmaxf(acc[3] * BN_SCALE_F, 0.f);
      *(float4*)(&sm.l.z[tl][og * 4]) = zv;
    } else {
      int lane5 = tid - 256;
      int og = lane5 >> 4;
      int tlo = lane5 & 15;
      if (tlo < 11) {
        int tl = 64 + tlo;
        float acc[4] = {0.f, 0.f, 0.f, 0.f};
        for (int c = 0; c < 64; ++c) {
          const float* wr = lw1r + c * 48 + og * 12;
          float pk0 = sm.l.p[c][tl];
          float pk1 = sm.l.p[c][tl + 1];
          float pk2 = sm.l.p[c][tl + 2];
#pragma unroll
          for (int oi = 0; oi < 4; ++oi) {
            acc[oi] = fmaf(wr[oi * 3 + 0], pk0, acc[oi]);
            acc[oi] = fmaf(wr[oi * 3 + 1], pk1, acc[oi]);
            acc[oi] = fmaf(wr[oi * 3 + 2], pk2, acc[oi]);
          }
        }
        float4 zv;
        zv.x = fmaxf(acc[0] * BN_SCALE_F, 0.f);
        zv.y = fmaxf(acc[1] * BN_SCALE_F, 0.f);
        zv.z = fmaxf(acc[2] * BN_SCALE_F, 0.f);
        zv.w = fmaxf(acc[3] * BN_SCALE_F, 0.f);
        *(float4*)(&sm.l.z[tl][og * 4]) = zv;
      }
    }
    __syncthreads();
    {
      // stage 2: write t-major laT[(n*300+t)*64 + c]
      int c = tid / 5;
      int ts = tid - c * 5;
      const float4* w2v = (const float4*)(l_w2 + c * 16);
      float4 wA = w2v[0], wB = w2v[1], wC = w2v[2], wD = w2v[3];
      float* outb = laT + ((size_t)n * 300 + t0) * 64 + c;
      for (int it = 0; it < 15; ++it) {
        int tl = ts + it * 5;
        const float4* zv = (const float4*)(&sm.l.z[tl][0]);
        float4 zA = zv[0], zB = zv[1], zC = zv[2], zD = zv[3];
        float s = zA.x * wA.x + zA.y * wA.y + zA.z * wA.z + zA.w * wA.w;
        s += zB.x * wB.x + zB.y * wB.y + zB.z * wB.z + zB.w * wB.w;
        s += zC.x * wC.x + zC.y * wC.y + zC.z * wC.z + zC.w * wC.w;
        s += zD.x * wD.x + zD.y * wD.y + zD.z * wD.z + zD.w * wD.w;
        outb[(size_t)tl * 64] = 1.f / (1.f + expf(-s));
      }
    }
  }
}

// ---------------- Kernel 3: final depthwise temporal conv (t-major la) ----------------
__global__ __launch_bounds__(256) void tam_final_kernel(const float* __restrict__ x,
                                                        const float* __restrict__ laT,
                                                        const float* __restrict__ kern,
                                                        float* __restrict__ out) {
  int bid = blockIdx.x;  // 64 n * 8 tchunk * 2 half
  int n = bid >> 4;
  int rem = bid & 15;
  int tch = rem >> 1;
  int half = rem & 1;
  int cv4 = half * 256 + threadIdx.x;
  if (cv4 >= 400) return;
  int e0 = cv4 * 4;
  int c0 = e0 / 25;
  int c3 = (e0 + 3) / 25;
  bool s1 = ((e0 + 1) / 25) != c0;
  bool s2 = ((e0 + 2) / 25) != c0;
  bool s3 = (c3 != c0);
  const float* lan = laT + (size_t)n * 300 * 64;  // + t*64 + c
  const float* kp0 = kern + (size_t)(n * 64 + c0) * 3;
  const float* kp1 = kern + (size_t)(n * 64 + c3) * 3;
  float k00 = kp0[0], k01 = kp0[1], k02 = kp0[2];
  float k10 = kp1[0], k11 = kp1[1], k12 = kp1[2];
  float4 K0 = {k00, s1 ? k10 : k00, s2 ? k10 : k00, s3 ? k10 : k00};
  float4 K1 = {k01, s1 ? k11 : k01, s2 ? k11 : k01, s3 ? k11 : k01};
  float4 K2 = {k02, s1 ? k12 : k02, s2 ? k12 : k02, s3 ? k12 : k02};

  const float4* xp = (const float4*)(x + (size_t)n * 480000) + cv4;
  float4* op = (float4*)(out + (size_t)n * 480000) + cv4;

  int t0 = tch * 38;
  int tend = t0 + 38;
  if (tend > 300) tend = 300;

#define LAMUL(dst, t)                                        \
  {                                                          \
    float l0 = lan[(size_t)(t) * 64 + c0];                   \
    float l1 = lan[(size_t)(t) * 64 + c3];                   \
    float4 xv = xp[(size_t)(t) * 400];                       \
    dst.x = xv.x * l0;                                       \
    dst.y = xv.y * (s1 ? l1 : l0);                           \
    dst.z = xv.z * (s2 ? l1 : l0);                           \
    dst.w = xv.w * (s3 ? l1 : l0);                           \
  }

  float4 am, ac, an;
  if (t0 > 0) {
    LAMUL(am, t0 - 1);
  } else {
    am = {0.f, 0.f, 0.f, 0.f};
  }
  LAMUL(ac, t0);
  for (int t = t0; t < tend; ++t) {
    if (t + 1 < 300) {
      LAMUL(an, t + 1);
    } else {
      an = {0.f, 0.f, 0.f, 0.f};
    }
    float4 o;
    o.x = fmaf(am.x, K0.x, fmaf(ac.x, K1.x, an.x * K2.x));
    o.y = fmaf(am.y, K0.y, fmaf(ac.y, K1.y, an.y * K2.y));
    o.z = fmaf(am.z, K0.z, fmaf(ac.z, K1.z, an.z * K2.z));
    o.w = fmaf(am.w, K0.w, fmaf(ac.w, K1.w, an.w * K2.w));
    op[(size_t)t * 400] = o;
    am = ac;
    ac = an;
  }
#undef LAMUL
}

extern "C" void kernel_launch(void* const* d_in, const int* in_sizes, int n_in,
                              void* d_out, int out_size, void* d_ws, size_t ws_size,
                              hipStream_t stream) {
  const float* x = (const float*)d_in[0];
  const float* g_w1 = (const float*)d_in[1];
  const float* g_w2 = (const float*)d_in[2];
  const float* l_w1 = (const float*)d_in[3];
  const float* l_w2 = (const float*)d_in[4];
  float* out = (float*)d_out;
  float* ws = (float*)d_ws;
  float* pooledT = ws;                                 // 1,228,800 floats
  float* kern = ws + 1228800;                          // 12,288
  float* laT = ws + 1228800 + 12288;                   // 1,228,800 (t-major)
  __hip_bfloat16* w1b = (__hip_bfloat16*)(ws + 2469888);  // 608*320 bf16
  float* lw1r = ws + 2469888 + 97280;                  // 3,072 floats

  hipLaunchKernelGGL(pool_kernel, dim3(4817), dim3(320), 0, stream, x, g_w1, l_w1,
                     pooledT, w1b, lw1r);
  hipLaunchKernelGGL(gl_kernel, dim3(512), dim3(320), 0, stream, pooledT, w1b,
                     g_w2, lw1r, l_w2, kern, laT);
  hipLaunchKernelGGL(tam_final_kernel, dim3(1024), dim3(256), 0, stream, x, laT, kern, out);
}

// Round 24
// 105.548 us; speedup vs baseline: 2.2815x; 1.0560x over previous
//
#include <hip/hip_runtime.h>
#include <hip/hip_bf16.h>
#include <math.h>

#define BN_SCALE_F 0.99999500003749969f

typedef short short8v __attribute__((ext_vector_type(8)));
typedef float float4v __attribute__((ext_vector_type(4)));

// x: [N=64][T=300][C=64][V=25] fp32
// pooledT: [19200][64] f32   (nt-major; coalesced)
// w1b:     [608][320]  bf16  (G MFMA B)
// kern: [4096][3]   la: [4096][300]   lw1r: [64][48]
// out stores are NONTEMPORAL (native-vector builtin): keep out of L3 so x
// (123MB) stays L3-resident across graph replays (x+out+ws ~= 256MB = L3 cap).

// ---------------- Kernel 1: pool (0..4799) + w1b (4800..4815) + lw1r (4816) ----------------
__global__ __launch_bounds__(320) void pool_kernel(const float* __restrict__ x,
                                                   const float* __restrict__ g_w1,
                                                   const float* __restrict__ l_w1,
                                                   float* __restrict__ pooledT,
                                                   __hip_bfloat16* __restrict__ w1b,
                                                   float* __restrict__ lw1r) {
  __shared__ float buf[6400];
  int bid = blockIdx.x;
  int tid = threadIdx.x;
  if (bid < 4800) {
    const float4* src = (const float4*)(x + (size_t)bid * 6400);
    float4* b4 = (float4*)buf;
#pragma unroll
    for (int it = 0; it < 5; ++it) {
      int i = tid + it * 320;
      b4[i] = src[i];
    }
    __syncthreads();
    int wave = tid >> 6;
    int c = tid & 63;
    if (wave < 4) {
      const float* p = buf + wave * 1600 + c * 25;
      float s = 0.f;
#pragma unroll
      for (int v = 0; v < 25; ++v) s += p[v];
      pooledT[(size_t)(bid * 4 + wave) * 64 + c] = s * 0.04f;
    }
  } else if (bid < 4816) {
    int b = bid - 4800;
    for (int i = b * 256 + tid; i < 608 * 320; i += 16 * 256) {
      int j = i / 320, k = i - j * 320;
      float v = (j < 600 && k < 300) ? g_w1[(size_t)j * 300 + k] : 0.f;
      w1b[i] = __float2bfloat16(v);
    }
  } else {
    for (int i = tid; i < 3072; i += 320) {
      int o = i / 192;
      int rem = i - o * 192;
      int c = rem / 3;
      int k = rem - c * 3;
      lw1r[c * 48 + o * 3 + k] = l_w1[i];
    }
  }
}

// ---------------- Kernel 2: merged G (MFMA, LDS-staged A) + L branch ----------------
union GLSmem {
  struct {
    __hip_bfloat16 abuf[16][328];
    __hip_bfloat16 hbuf[16][612];
    float logits[48];
  } g;
  struct {
    float p[64][81];
    float z[75][20];
  } l;
};

__global__ __launch_bounds__(320) void gl_kernel(const float* __restrict__ pooledT,
                                                 const __hip_bfloat16* __restrict__ w1b,
                                                 const float* __restrict__ g_w2,  // [3][600]
                                                 const float* __restrict__ lw1r,  // [64][48]
                                                 const float* __restrict__ l_w2,  // [64][16]
                                                 float* __restrict__ kern,        // [4096][3]
                                                 float* __restrict__ la) {        // [4096][300]
  __shared__ GLSmem sm;
  int bid = blockIdx.x;
  int tid = threadIdx.x;
  int wave = tid >> 6, lane = tid & 63;
  if (bid < 256) {
    // ---- G branch ----
    int r0 = bid * 16;
    int n = bid >> 2;
    int c0 = (bid & 3) * 16;
    for (int i = tid; i < 5120; i += 320) {
      int tt = i >> 4;
      int cc = i & 15;
      float v = (tt < 300) ? pooledT[((size_t)n * 300 + tt) * 64 + c0 + cc] : 0.f;
      sm.g.abuf[cc][tt] = __float2bfloat16(v);
    }
    __syncthreads();

    int row16 = lane & 15;
    int k8 = (lane >> 4) * 8;

    float4v acc[8];
#pragma unroll
    for (int q = 0; q < 8; ++q) acc[q] = (float4v){0.f, 0.f, 0.f, 0.f};

    const short* pb = (const short*)w1b + k8;
    const short* pa = (const short*)&sm.g.abuf[row16][k8];

    for (int kt = 0; kt < 10; ++kt) {
      short8v av = *(const short8v*)(pa + kt * 32);
#pragma unroll
      for (int q = 0; q < 8; ++q) {
        int jt = wave + 5 * q;
        if (jt < 38) {
          short8v bv = *(const short8v*)(pb + (size_t)(jt * 16 + row16) * 320 + kt * 32);
          acc[q] = __builtin_amdgcn_mfma_f32_16x16x32_bf16(av, bv, acc[q], 0, 0, 0);
        }
      }
    }

#pragma unroll
    for (int q = 0; q < 8; ++q) {
      int jt = wave + 5 * q;
      if (jt < 38) {
        int col = jt * 16 + row16;
#pragma unroll
        for (int reg = 0; reg < 4; ++reg) {
          int i = (lane >> 4) * 4 + reg;
          sm.g.hbuf[i][col] = __float2bfloat16(fmaxf(acc[q][reg] * BN_SCALE_F, 0.f));
        }
      }
    }
    __syncthreads();

    for (int o = wave; o < 48; o += 5) {
      int r = o / 3, k = o - r * 3;
      float s = 0.f;
#pragma unroll
      for (int q = 0; q < 10; ++q) {
        int jj = lane + q * 64;
        if (jj < 600) s = fmaf(__bfloat162float(sm.g.hbuf[r][jj]), g_w2[k * 600 + jj], s);
      }
#pragma unroll
      for (int off = 1; off < 64; off <<= 1) s += __shfl_xor(s, off, 64);
      if (lane == 0) sm.g.logits[o] = s;
    }
    __syncthreads();
    if (tid < 16) {
      float a = sm.g.logits[tid * 3 + 0];
      float b = sm.g.logits[tid * 3 + 1];
      float c = sm.g.logits[tid * 3 + 2];
      float m = fmaxf(a, fmaxf(b, c));
      float ea = expf(a - m), eb = expf(b - m), ec = expf(c - m);
      float inv = 1.f / (ea + eb + ec);
      size_t o = (size_t)(r0 + tid) * 3;
      kern[o] = ea * inv;
      kern[o + 1] = eb * inv;
      kern[o + 2] = ec * inv;
    }
  } else {
    // ---- L branch ----
    int bid2 = bid - 256;
    int n = bid2 >> 2;
    int tc = bid2 & 3;
    int t0 = tc * 75;
    for (int i = tid; i < 77 * 64; i += 320) {
      int tt = i >> 6, c = i & 63;
      int gt = t0 - 1 + tt;
      sm.l.p[c][tt] = (gt >= 0 && gt < 300) ? pooledT[((size_t)n * 300 + gt) * 64 + c] : 0.f;
    }
    __syncthreads();
    if (tid < 256) {
      int og = __builtin_amdgcn_readfirstlane(tid >> 6);
      int tl = tid & 63;
      float acc[4] = {0.f, 0.f, 0.f, 0.f};
      const float* wb = lw1r + og * 12;
      for (int c = 0; c < 64; ++c) {
        const float* wr = wb + c * 48;  // uniform -> s_load_dwordx4
        float pk0 = sm.l.p[c][tl];
        float pk1 = sm.l.p[c][tl + 1];
        float pk2 = sm.l.p[c][tl + 2];
#pragma unroll
        for (int oi = 0; oi < 4; ++oi) {
          acc[oi] = fmaf(wr[oi * 3 + 0], pk0, acc[oi]);
          acc[oi] = fmaf(wr[oi * 3 + 1], pk1, acc[oi]);
          acc[oi] = fmaf(wr[oi * 3 + 2], pk2, acc[oi]);
        }
      }
      float4 zv;
      zv.x = fmaxf(acc[0] * BN_SCALE_F, 0.f);
      zv.y = fmaxf(acc[1] * BN_SCALE_F, 0.f);
      zv.z = fmaxf(acc[2] * BN_SCALE_F, 0.f);
      zv.w = fmaxf(acc[3] * BN_SCALE_F, 0.f);
      *(float4*)(&sm.l.z[tl][og * 4]) = zv;
    } else {
      int lane5 = tid - 256;
      int og = lane5 >> 4;
      int tlo = lane5 & 15;
      if (tlo < 11) {
        int tl = 64 + tlo;
        float acc[4] = {0.f, 0.f, 0.f, 0.f};
        for (int c = 0; c < 64; ++c) {
          const float* wr = lw1r + c * 48 + og * 12;
          float pk0 = sm.l.p[c][tl];
          float pk1 = sm.l.p[c][tl + 1];
          float pk2 = sm.l.p[c][tl + 2];
#pragma unroll
          for (int oi = 0; oi < 4; ++oi) {
            acc[oi] = fmaf(wr[oi * 3 + 0], pk0, acc[oi]);
            acc[oi] = fmaf(wr[oi * 3 + 1], pk1, acc[oi]);
            acc[oi] = fmaf(wr[oi * 3 + 2], pk2, acc[oi]);
          }
        }
        float4 zv;
        zv.x = fmaxf(acc[0] * BN_SCALE_F, 0.f);
        zv.y = fmaxf(acc[1] * BN_SCALE_F, 0.f);
        zv.z = fmaxf(acc[2] * BN_SCALE_F, 0.f);
        zv.w = fmaxf(acc[3] * BN_SCALE_F, 0.f);
        *(float4*)(&sm.l.z[tl][og * 4]) = zv;
      }
    }
    __syncthreads();
    {
      int c = tid / 5;
      int ts = tid - c * 5;
      const float4* w2v = (const float4*)(l_w2 + c * 16);
      float4 wA = w2v[0], wB = w2v[1], wC = w2v[2], wD = w2v[3];
      float* outp = la + (size_t)(n * 64 + c) * 300 + t0;
      for (int it = 0; it < 15; ++it) {
        int tl = ts + it * 5;
        const float4* zv = (const float4*)(&sm.l.z[tl][0]);
        float4 zA = zv[0], zB = zv[1], zC = zv[2], zD = zv[3];
        float s = zA.x * wA.x + zA.y * wA.y + zA.z * wA.z + zA.w * wA.w;
        s += zB.x * wB.x + zB.y * wB.y + zB.z * wB.z + zB.w * wB.w;
        s += zC.x * wC.x + zC.y * wC.y + zC.z * wC.z + zC.w * wC.w;
        s += zD.x * wD.x + zD.y * wD.y + zD.z * wD.z + zD.w * wD.w;
        outp[tl] = 1.f / (1.f + expf(-s));
      }
    }
  }
}

// ---------------- Kernel 3: final depthwise temporal conv (nontemporal out) ----------------
__global__ __launch_bounds__(256) void tam_final_kernel(const float* __restrict__ x,
                                                        const float* __restrict__ la,
                                                        const float* __restrict__ kern,
                                                        float* __restrict__ out) {
  int bid = blockIdx.x;  // 64 n * 8 tchunk * 2 half
  int n = bid >> 4;
  int rem = bid & 15;
  int tch = rem >> 1;
  int half = rem & 1;
  int cv4 = half * 256 + threadIdx.x;
  if (cv4 >= 400) return;
  int e0 = cv4 * 4;
  int c0 = e0 / 25;
  int c3 = (e0 + 3) / 25;
  bool s1 = ((e0 + 1) / 25) != c0;
  bool s2 = ((e0 + 2) / 25) != c0;
  bool s3 = (c3 != c0);
  const float* lap0 = la + (size_t)(n * 64 + c0) * 300;
  const float* lap1 = la + (size_t)(n * 64 + c3) * 300;
  const float* kp0 = kern + (size_t)(n * 64 + c0) * 3;
  const float* kp1 = kern + (size_t)(n * 64 + c3) * 3;
  float k00 = kp0[0], k01 = kp0[1], k02 = kp0[2];
  float k10 = kp1[0], k11 = kp1[1], k12 = kp1[2];
  float4 K0 = {k00, s1 ? k10 : k00, s2 ? k10 : k00, s3 ? k10 : k00};
  float4 K1 = {k01, s1 ? k11 : k01, s2 ? k11 : k01, s3 ? k11 : k01};
  float4 K2 = {k02, s1 ? k12 : k02, s2 ? k12 : k02, s3 ? k12 : k02};

  const float4* xp = (const float4*)(x + (size_t)n * 480000) + cv4;
  float4v* op = (float4v*)(out + (size_t)n * 480000) + cv4;

  int t0 = tch * 38;
  int tend = t0 + 38;
  if (tend > 300) tend = 300;

#define LAMUL(dst, t)                                        \
  {                                                          \
    float l0 = lap0[(t)];                                    \
    float l1 = lap1[(t)];                                    \
    float4 xv = xp[(size_t)(t) * 400];                       \
    dst.x = xv.x * l0;                                       \
    dst.y = xv.y * (s1 ? l1 : l0);                           \
    dst.z = xv.z * (s2 ? l1 : l0);                           \
    dst.w = xv.w * (s3 ? l1 : l0);                           \
  }

  float4 am, ac, an;
  if (t0 > 0) {
    LAMUL(am, t0 - 1);
  } else {
    am = {0.f, 0.f, 0.f, 0.f};
  }
  LAMUL(ac, t0);
  for (int t = t0; t < tend; ++t) {
    if (t + 1 < 300) {
      LAMUL(an, t + 1);
    } else {
      an = {0.f, 0.f, 0.f, 0.f};
    }
    float4v o;
    o[0] = fmaf(am.x, K0.x, fmaf(ac.x, K1.x, an.x * K2.x));
    o[1] = fmaf(am.y, K0.y, fmaf(ac.y, K1.y, an.y * K2.y));
    o[2] = fmaf(am.z, K0.z, fmaf(ac.z, K1.z, an.z * K2.z));
    o[3] = fmaf(am.w, K0.w, fmaf(ac.w, K1.w, an.w * K2.w));
    __builtin_nontemporal_store(o, &op[(size_t)t * 400]);  // nt: don't evict x from L3
    am = ac;
    ac = an;
  }
#undef LAMUL
}

extern "C" void kernel_launch(void* const* d_in, const int* in_sizes, int n_in,
                              void* d_out, int out_size, void* d_ws, size_t ws_size,
                              hipStream_t stream) {
  const float* x = (const float*)d_in[0];
  const float* g_w1 = (const float*)d_in[1];
  const float* g_w2 = (const float*)d_in[2];
  const float* l_w1 = (const float*)d_in[3];
  const float* l_w2 = (const float*)d_in[4];
  float* out = (float*)d_out;
  float* ws = (float*)d_ws;
  float* pooledT = ws;                                 // 1,228,800 floats
  float* kern = ws + 1228800;                          // 12,288
  float* lact = ws + 1228800 + 12288;                  // 1,228,800
  __hip_bfloat16* w1b = (__hip_bfloat16*)(ws + 2469888);  // 608*320 bf16
  float* lw1r = ws + 2469888 + 97280;                  // 3,072 floats

  hipLaunchKernelGGL(pool_kernel, dim3(4817), dim3(320), 0, stream, x, g_w1, l_w1,
                     pooledT, w1b, lw1r);
  hipLaunchKernelGGL(gl_kernel, dim3(512), dim3(320), 0, stream, pooledT, w1b,
                     g_w2, lw1r, l_w2, kern, lact);
  hipLaunchKernelGGL(tam_final_kernel, dim3(1024), dim3(256), 0, stream, x, lact, kern, out);
}